// Round 4
// baseline (600.148 us; speedup 1.0000x reference)
//
#include <hip/hip_runtime.h>
#include <hip/hip_bf16.h>

#define B_ 8
#define C_ 1536
#define T_ 4096
#define A_ 128
#define K3_ 4608        // 3*C columns of W1
#define M32_ 128        // T / 32 chunks
#define SCW_ 104        // k2g scratch row stride (f16 elems), 16B-aligned

typedef _Float16 h8  __attribute__((ext_vector_type(8)));
typedef float    f4  __attribute__((ext_vector_type(4)));

// ---------------- kernel 0: W1 fp32 -> f16, MFMA A-fragment order -----------
// W1f[((kb*8 + t8)*64 + lane)*8 + j] = W1[a=t8*16+(lane&15)][k=kb*32+(lane>>4)*8+j]
__global__ void k0_pack(const float* __restrict__ W1, _Float16* __restrict__ W1f) {
    int i = blockIdx.x * 256 + threadIdx.x;
    if (i >= A_ * K3_) return;
    int a = i / K3_, k = i - a * K3_;
    int t8 = a >> 4, r15 = a & 15;
    int kb = k >> 5, q = (k >> 3) & 3, j = k & 7;
    int lane = q * 16 + r15;
    W1f[(size_t)((kb * 8 + t8) * 64 + lane) * 8 + j] = (_Float16)W1[i];
}

// ---------------- kernel 1: per-(b,c) 32-t-chunk carries (row-major) --------
__global__ __launch_bounds__(256) void k1_carry(
    const float* __restrict__ x, const int* __restrict__ lens,
    float2* __restrict__ carry)
{
    const int rowid = blockIdx.x * 4 + (threadIdx.x >> 6);
    const int lane  = threadIdx.x & 63;
    const int b     = rowid / C_;
    const int len   = lens[b];
    const float* xr = x + (size_t)rowid * T_;
    float2* cp = carry + (size_t)rowid * M32_;
    const int grp = lane >> 3;
    float base1 = 0.f, base2 = 0.f;
#pragma unroll
    for (int g = 0; g < 16; ++g) {
        const int t0g = g * 256;
        if (t0g >= len) {
            if ((lane & 7) == 0) cp[g * 8 + grp] = make_float2(base1, base2);
            continue;
        }
        float4 v = *(const float4*)(xr + t0g + lane * 4);
        float s1, s2;
        if (t0g + 256 <= len) {
            s1 = v.x + v.y + v.z + v.w;
            s2 = v.x * v.x + v.y * v.y + v.z * v.z + v.w * v.w;
        } else {
            const int tb = t0g + lane * 4;
            float vs[4] = {v.x, v.y, v.z, v.w};
            s1 = 0.f; s2 = 0.f;
#pragma unroll
            for (int j = 0; j < 4; ++j) {
                float m = (tb + j < len) ? vs[j] : 0.f;
                s1 += m; s2 += m * vs[j];
            }
        }
        float g1 = s1, g2 = s2;
        g1 += __shfl_xor(g1, 1, 64); g2 += __shfl_xor(g2, 1, 64);
        g1 += __shfl_xor(g1, 2, 64); g2 += __shfl_xor(g2, 2, 64);
        g1 += __shfl_xor(g1, 4, 64); g2 += __shfl_xor(g2, 4, 64);
        float V1 = g1, V2 = g2;
#pragma unroll
        for (int d = 8; d < 64; d <<= 1) {
            float o1 = __shfl_up(V1, d, 64);
            float o2 = __shfl_up(V2, d, 64);
            if (lane >= d) { V1 += o1; V2 += o2; }
        }
        const float e1 = V1 - g1, e2 = V2 - g2;
        if ((lane & 7) == 0) cp[g * 8 + grp] = make_float2(base1 + e1, base2 + e2);
        base1 += __shfl(V1, 63, 64);
        base2 += __shfl(V2, 63, 64);
    }
}

// ---------------- kernel 1b: carry transpose -> carryT[b][m][c] -------------
__global__ __launch_bounds__(256) void k1b_T(
    const float2* __restrict__ carry, float2* __restrict__ carryT)
{
    __shared__ float2 t[64][65];
    const int bid = blockIdx.x;        // 8 * 24 * 2 = 384
    const int b = bid / 48;
    const int r = bid - b * 48;
    const int ct = r >> 1, mt = r & 1;
    const int c0 = ct * 64, m0 = mt * 64;
    const int tx = threadIdx.x & 63, ty = threadIdx.x >> 6;
#pragma unroll
    for (int i = 0; i < 16; ++i) {
        int cl = i * 4 + ty;
        t[cl][tx] = carry[((size_t)(b * C_ + c0 + cl)) * M32_ + m0 + tx];
    }
    __syncthreads();
#pragma unroll
    for (int i = 0; i < 16; ++i) {
        int ml = i * 4 + ty;
        carryT[((size_t)b * M32_ + m0 + ml) * C_ + c0 + tx] = t[tx][ml];
    }
}

// ---------------- kernel 2g: fused stats+GEMM, 4-way split-K ----------------
// grid 1024 = (b, 32-t chunk m). 4 waves = 4 K-quarters (384 ch = 12 steps).
// -> 4 blocks/CU, 4 waves/SIMD (vs round-3's 2): latency now hidden by TLP.
// af L2 traffic unchanged (K-split partitions W1f per chunk, no duplication).
// Main loop barrier-free (wave-private scratch); 4 barriers in reduce tail.
__global__ __launch_bounds__(256, 4) void k2g(
    const float* __restrict__ x, const int* __restrict__ lens,
    const float2* __restrict__ carryT, const _Float16* __restrict__ W1f,
    const float* __restrict__ b1, const float* __restrict__ W2,
    float* __restrict__ logits)
{
    __shared__ __align__(16) char smem[32768];   // scratch 26.6KB / reduce 32KB
    __shared__ float s_b1[A_], s_w2[A_];

    const int tid = threadIdx.x, lane = tid & 63, w = tid >> 6;
    const int bid = blockIdx.x;
    const int b   = bid >> 7;
    const int m   = bid & 127;
    const int t0  = m << 5;
    const int len = lens[b];
    if (tid < A_) { s_b1[tid] = b1[tid]; s_w2[tid] = W2[tid]; }

    const int kc = lane >> 1;            // channel within 32-group
    const int th = lane & 1;             // t-half (16 t)
    const int c_base = w * 384;          // wave's K-quarter
    _Float16* sc = (_Float16*)smem + w * (32 * SCW_);
    const h8* W1f8 = (const h8*)W1f;
    const bool full = (t0 + 32) <= len;  // wave-uniform
    const int tb = t0 + th * 16;

    f4 acc[2][8] = {};

    const float* xptr = x + ((size_t)b * C_ + c_base + kc) * T_ + tb;
    float4 xv0 = ((const float4*)xptr)[0];
    float4 xv1 = ((const float4*)xptr)[1];
    float4 xv2 = ((const float4*)xptr)[2];
    float4 xv3 = ((const float4*)xptr)[3];

    for (int step = 0; step < 12; ++step) {
        float xs[16];
        *(float4*)&xs[0]  = xv0; *(float4*)&xs[4]  = xv1;
        *(float4*)&xs[8]  = xv2; *(float4*)&xs[12] = xv3;
        if (step < 11) {                 // prefetch next c-step
            xptr += 32 * (size_t)T_;
            xv0 = ((const float4*)xptr)[0];
            xv1 = ((const float4*)xptr)[1];
            xv2 = ((const float4*)xptr)[2];
            xv3 = ((const float4*)xptr)[3];
        }
        const float2 cr =
            carryT[((size_t)b * M32_ + m) * C_ + c_base + step * 32 + kc];

        // lane totals over its 16 t
        float ls1 = 0.f, ls2 = 0.f;
        if (full) {
#pragma unroll
            for (int j = 0; j < 16; ++j) { ls1 += xs[j]; ls2 += xs[j] * xs[j]; }
        } else {
#pragma unroll
            for (int j = 0; j < 16; ++j) {
                float mv = (tb + j < len) ? xs[j] : 0.f;
                ls1 += mv; ls2 += mv * xs[j];
            }
        }
        const float o1 = __shfl_xor(ls1, 1, 64);
        const float o2 = __shfl_xor(ls2, 1, 64);
        float r1 = cr.x + (th ? o1 : 0.f);
        float r2 = cr.y + (th ? o2 : 0.f);
#pragma unroll
        for (int j = 0; j < 16; ++j) {
            const float xval = xs[j];
            const float mv = (full || (tb + j < len)) ? xval : 0.f;
            r1 += mv; r2 += mv * xval;
            const float rn = __builtin_amdgcn_rcpf((float)min(tb + j + 1, len));
            const float mn = r1 * rn;
            const float var = r2 * rn - mn * mn;
            const float sd = sqrtf(fmaxf(var, 1e-12f));
            const int row = th * 16 + j;
            sc[row * SCW_ + kc]      = (_Float16)xval;
            sc[row * SCW_ + 32 + kc] = (_Float16)mn;
            sc[row * SCW_ + 64 + kc] = (_Float16)sd;
        }
        // within-wave LDS ordering via lgkmcnt; no barrier needed
        const int t15 = lane & 15, k8 = lane >> 4;
        const int kbS = w * 12 + step;
#pragma unroll
        for (int p = 0; p < 3; ++p) {
            h8 bf0 = *(const h8*)&sc[t15 * SCW_ + p * 32 + k8 * 8];
            h8 bf1 = *(const h8*)&sc[(16 + t15) * SCW_ + p * 32 + k8 * 8];
            const int kb = p * 48 + kbS;
#pragma unroll
            for (int ii = 0; ii < 8; ++ii) {
                h8 af = W1f8[(size_t)(kb * 8 + ii) * 64 + lane];
                acc[0][ii] = __builtin_amdgcn_mfma_f32_16x16x32_f16(af, bf0, acc[0][ii], 0, 0, 0);
                acc[1][ii] = __builtin_amdgcn_mfma_f32_16x16x32_f16(af, bf1, acc[1][ii], 0, 0, 0);
            }
        }
    }

    // ---- 4-way split-K reduce cascade + epilogue (4 barriers, loop-free) ----
    __syncthreads();
    float* red = (float*)smem;
    if (w >= 2) {
        float* r = red + (size_t)(w - 2) * 4096;
#pragma unroll
        for (int nn = 0; nn < 2; ++nn)
#pragma unroll
            for (int ii = 0; ii < 8; ++ii)
#pragma unroll
                for (int rg = 0; rg < 4; ++rg)
                    r[(nn * 32 + ii * 4 + rg) * 64 + lane] = acc[nn][ii][rg];
    }
    __syncthreads();
    if (w < 2) {
        float* r = red + (size_t)w * 4096;
#pragma unroll
        for (int nn = 0; nn < 2; ++nn)
#pragma unroll
            for (int ii = 0; ii < 8; ++ii)
#pragma unroll
                for (int rg = 0; rg < 4; ++rg)
                    acc[nn][ii][rg] += r[(nn * 32 + ii * 4 + rg) * 64 + lane];
    }
    __syncthreads();
    if (w == 1) {
#pragma unroll
        for (int nn = 0; nn < 2; ++nn)
#pragma unroll
            for (int ii = 0; ii < 8; ++ii)
#pragma unroll
                for (int rg = 0; rg < 4; ++rg)
                    red[(nn * 32 + ii * 4 + rg) * 64 + lane] = acc[nn][ii][rg];
    }
    __syncthreads();
    if (w == 0) {
        const int q = lane >> 4;
#pragma unroll
        for (int nn = 0; nn < 2; ++nn) {
            float pr = 0.f;
#pragma unroll
            for (int ii = 0; ii < 8; ++ii)
#pragma unroll
                for (int rg = 0; rg < 4; ++rg) {
                    float v = acc[nn][ii][rg] + red[(nn * 32 + ii * 4 + rg) * 64 + lane];
                    int a = ii * 16 + q * 4 + rg;
                    pr += tanhf(v + s_b1[a]) * s_w2[a];
                }
            pr += __shfl_xor(pr, 16, 64);
            pr += __shfl_xor(pr, 32, 64);
            if (lane < 16)
                logits[(size_t)b * T_ + t0 + nn * 16 + lane] = pr;
        }
    }
}

// ---------------- kernel 3: softmax prep (e, cumsum Z) per b ----------------
// b2 and the max-subtraction cancel in the e/Z ratios used downstream.
__global__ __launch_bounds__(1024) void k3_softmax(
    const float* __restrict__ logits, float* __restrict__ earr,
    float* __restrict__ zarr)
{
    __shared__ float wsum[16];
    const int b = blockIdx.x, tid = threadIdx.x, lane = tid & 63, w = tid >> 6;
    float4 v = *(const float4*)(logits + (size_t)b * T_ + tid * 4);
    float e0 = expf(v.x), e1 = expf(v.y), e2 = expf(v.z), e3 = expf(v.w);
    float s = (e0 + e1) + (e2 + e3);
    float V = s;
#pragma unroll
    for (int d = 1; d < 64; d <<= 1) {
        float o = __shfl_up(V, d, 64);
        if (lane >= d) V += o;
    }
    if (lane == 63) wsum[w] = V;
    __syncthreads();
    float wb = 0.f;
#pragma unroll
    for (int i = 0; i < 16; ++i) wb += (i < w) ? wsum[i] : 0.f;
    float run = wb + (V - s);
    float4 ev, zv;
    ev.x = e0; run += e0; zv.x = run;
    ev.y = e1; run += e1; zv.y = run;
    ev.z = e2; run += e2; zv.z = run;
    ev.w = e3; run += e3; zv.w = run;
    *(float4*)(earr + (size_t)b * T_ + tid * 4) = ev;
    *(float4*)(zarr + (size_t)b * T_ + tid * 4) = zv;
}

// ---------------- kernel 4: weighted running mean/std + final reduce --------
__global__ __launch_bounds__(256) void k4_wstats(
    const float* __restrict__ x, const float* __restrict__ earr,
    const float* __restrict__ zarr, float* __restrict__ out)
{
    const int rowid = blockIdx.x * 4 + (threadIdx.x >> 6);
    const int lane  = threadIdx.x & 63;
    const int b = rowid / C_;
    const int c = rowid - b * C_;
    const float* xr = x + (size_t)rowid * T_;
    const float* er = earr + (size_t)b * T_;
    const float* zr = zarr + (size_t)b * T_;
    float am = 0.f, asd = 0.f;
    float baseS = 0.f, baseD = 0.f;
#pragma unroll
    for (int g = 0; g < 16; ++g) {
        const int off = g * 256 + lane * 4;
        float4 xv = *(const float4*)(xr + off);
        float4 ev = *(const float4*)(er + off);
        float4 zv = *(const float4*)(zr + off);
        float s0 = ev.x * xv.x;
        float s1 = s0 + ev.y * xv.y;
        float s2 = s1 + ev.z * xv.z;
        float s3 = s2 + ev.w * xv.w;
        float V = s3;
#pragma unroll
        for (int d = 1; d < 64; d <<= 1) {
            float o = __shfl_up(V, d, 64);
            if (lane >= d) V += o;
        }
        const float Sx = baseS + (V - s3);
        baseS += __shfl(V, 63, 64);
        const float rz0 = __builtin_amdgcn_rcpf(zv.x);
        const float rz1 = __builtin_amdgcn_rcpf(zv.y);
        const float rz2 = __builtin_amdgcn_rcpf(zv.z);
        const float rz3 = __builtin_amdgcn_rcpf(zv.w);
        const float wm0 = (Sx + s0) * rz0;
        const float wm1 = (Sx + s1) * rz1;
        const float wm2 = (Sx + s2) * rz2;
        const float wm3 = (Sx + s3) * rz3;
        am += (wm0 + wm1) + (wm2 + wm3);
        const float d0 = xv.x - wm0;
        const float d1 = xv.y - wm1;
        const float d2 = xv.z - wm2;
        const float d3 = xv.w - wm3;
        float q0 = ev.x * d0 * d0;
        float q1 = q0 + ev.y * d1 * d1;
        float q2 = q1 + ev.z * d2 * d2;
        float q3 = q2 + ev.w * d3 * d3;
        float W = q3;
#pragma unroll
        for (int d = 1; d < 64; d <<= 1) {
            float o = __shfl_up(W, d, 64);
            if (lane >= d) W += o;
        }
        const float Dx = baseD + (W - q3);
        baseD += __shfl(W, 63, 64);
        const float v0 = (Dx + q0) * rz0;
        const float v1 = (Dx + q1) * rz1;
        const float v2 = (Dx + q2) * rz2;
        const float v3 = (Dx + q3) * rz3;
        asd += (sqrtf(fmaxf(v0, 1e-12f)) + sqrtf(fmaxf(v1, 1e-12f)))
             + (sqrtf(fmaxf(v2, 1e-12f)) + sqrtf(fmaxf(v3, 1e-12f)));
    }
#pragma unroll
    for (int d = 1; d < 64; d <<= 1) {
        am  += __shfl_xor(am, d, 64);
        asd += __shfl_xor(asd, d, 64);
    }
    if (lane == 0) {
        out[(size_t)b * (2 * C_) + c]      = am  * (1.f / 4096.f);
        out[(size_t)b * (2 * C_) + C_ + c] = asd * (1.f / 4096.f);
    }
}

extern "C" void kernel_launch(void* const* d_in, const int* in_sizes, int n_in,
                              void* d_out, int out_size, void* d_ws, size_t ws_size,
                              hipStream_t stream) {
    const float* x    = (const float*)d_in[0];
    const int*   lens = (const int*)d_in[1];
    const float* W1   = (const float*)d_in[2];
    const float* b1   = (const float*)d_in[3];
    const float* W2   = (const float*)d_in[4];
    float* out = (float*)d_out;
    char* ws = (char*)d_ws;

    // ws layout (~26.8 MB):
    float2*    carry  = (float2*)ws;                     // 8*1536*128*8 = 12,582,912
    float2*    carryT = (float2*)(ws + 12582912);        //               12,582,912
    _Float16*  W1f    = (_Float16*)(ws + 25165824);      //                1,179,648
    float*     logits = (float*)(ws + 26345472);         //                  131,072
    float*     earr   = (float*)(ws + 26476544);         //                  131,072
    float*     zarr   = (float*)(ws + 26607616);         //                  131,072

    k0_pack   <<<(A_ * K3_ + 255) / 256, 256, 0, stream>>>(W1, W1f);
    k1_carry  <<<(B_ * C_) / 4, 256, 0, stream>>>(x, lens, carry);
    k1b_T     <<<B_ * 48, 256, 0, stream>>>(carry, carryT);
    k2g       <<<B_ * M32_, 256, 0, stream>>>(x, lens, carryT, W1f, b1, W2, logits);
    k3_softmax<<<B_, 1024, 0, stream>>>(logits, earr, zarr);
    k4_wstats <<<(B_ * C_) / 4, 256, 0, stream>>>(x, earr, zarr, out);
}

// Round 5
// 481.037 us; speedup vs baseline: 1.2476x; 1.2476x over previous
//
#include <hip/hip_runtime.h>
#include <hip/hip_bf16.h>

#define B_ 8
#define C_ 1536
#define T_ 4096
#define A_ 128
#define K3_ 4608        // 3*C columns of W1
#define M32_ 128        // T / 32 chunks
#define SCW_ 104        // k2g scratch row stride (f16 elems), 16B-aligned

typedef _Float16 h8  __attribute__((ext_vector_type(8)));
typedef float    f4  __attribute__((ext_vector_type(4)));

// ---------------- kernel 0: W1 fp32 -> f16, MFMA A-fragment order -----------
// W1f[((kb*8 + t8)*64 + lane)*8 + j] = W1[a=t8*16+(lane&15)][k=kb*32+(lane>>4)*8+j]
__global__ void k0_pack(const float* __restrict__ W1, _Float16* __restrict__ W1f) {
    int i = blockIdx.x * 256 + threadIdx.x;
    if (i >= A_ * K3_) return;
    int a = i / K3_, k = i - a * K3_;
    int t8 = a >> 4, r15 = a & 15;
    int kb = k >> 5, q = (k >> 3) & 3, j = k & 7;
    int lane = q * 16 + r15;
    W1f[(size_t)((kb * 8 + t8) * 64 + lane) * 8 + j] = (_Float16)W1[i];
}

// ---------------- kernel 1: per-(b,c) 32-t-chunk carries -> carryT ----------
// Coalesced x loads (lane L owns float4 g*64+L). Writes DIRECTLY in the
// transposed layout carryT[b][m][c] (8 scattered 8B stores per g, 12.6 MB
// total) -- k1b transpose kernel deleted.
__global__ __launch_bounds__(256) void k1_carryT(
    const float* __restrict__ x, const int* __restrict__ lens,
    float2* __restrict__ carryT)
{
    const int rowid = blockIdx.x * 4 + (threadIdx.x >> 6);
    const int lane  = threadIdx.x & 63;
    const int b     = rowid / C_;
    const int c     = rowid - b * C_;
    const int len   = lens[b];
    const float* xr = x + (size_t)rowid * T_;
    float2* ct = carryT + (size_t)b * M32_ * C_ + c;
    const int grp = lane >> 3;
    float base1 = 0.f, base2 = 0.f;
#pragma unroll
    for (int g = 0; g < 16; ++g) {
        const int t0g = g * 256;
        if (t0g >= len) {
            if ((lane & 7) == 0) ct[(size_t)(g * 8 + grp) * C_] = make_float2(base1, base2);
            continue;
        }
        float4 v = *(const float4*)(xr + t0g + lane * 4);
        float s1, s2;
        if (t0g + 256 <= len) {
            s1 = v.x + v.y + v.z + v.w;
            s2 = v.x * v.x + v.y * v.y + v.z * v.z + v.w * v.w;
        } else {
            const int tb = t0g + lane * 4;
            float vs[4] = {v.x, v.y, v.z, v.w};
            s1 = 0.f; s2 = 0.f;
#pragma unroll
            for (int j = 0; j < 4; ++j) {
                float m = (tb + j < len) ? vs[j] : 0.f;
                s1 += m; s2 += m * vs[j];
            }
        }
        float g1 = s1, g2 = s2;
        g1 += __shfl_xor(g1, 1, 64); g2 += __shfl_xor(g2, 1, 64);
        g1 += __shfl_xor(g1, 2, 64); g2 += __shfl_xor(g2, 2, 64);
        g1 += __shfl_xor(g1, 4, 64); g2 += __shfl_xor(g2, 4, 64);
        float V1 = g1, V2 = g2;
#pragma unroll
        for (int d = 8; d < 64; d <<= 1) {
            float o1 = __shfl_up(V1, d, 64);
            float o2 = __shfl_up(V2, d, 64);
            if (lane >= d) { V1 += o1; V2 += o2; }
        }
        const float e1 = V1 - g1, e2 = V2 - g2;
        if ((lane & 7) == 0)
            ct[(size_t)(g * 8 + grp) * C_] = make_float2(base1 + e1, base2 + e2);
        base1 += __shfl(V1, 63, 64);
        base2 += __shfl(V2, 63, 64);
    }
}

// ---------------- kernel 2g: fused stats+GEMM, 4-way split-K ----------------
// grid 1024 = (b, 32-t chunk m). 4 waves = 4 K-quarters (384 ch = 12 steps).
// __launch_bounds__(256,3): unified VGPR+AGPR cap 170 >= measured ~152 ->
// NO spill (round 4's (256,4) cap 128 caused 296MB scratch writes).
// 3 blocks/CU; main loop barrier-free (wave-private scratch).
__global__ __launch_bounds__(256, 3) void k2g(
    const float* __restrict__ x, const int* __restrict__ lens,
    const float2* __restrict__ carryT, const _Float16* __restrict__ W1f,
    const float* __restrict__ b1, const float* __restrict__ W2,
    float* __restrict__ logits)
{
    __shared__ __align__(16) char smem[32768];   // scratch 26.6KB / reduce 32KB
    __shared__ float s_b1[A_], s_w2[A_];

    const int tid = threadIdx.x, lane = tid & 63, w = tid >> 6;
    const int bid = blockIdx.x;
    const int b   = bid >> 7;
    const int m   = bid & 127;
    const int t0  = m << 5;
    const int len = lens[b];
    if (tid < A_) { s_b1[tid] = b1[tid]; s_w2[tid] = W2[tid]; }

    const int kc = lane >> 1;            // channel within 32-group
    const int th = lane & 1;             // t-half (16 t)
    const int c_base = w * 384;          // wave's K-quarter
    _Float16* sc = (_Float16*)smem + w * (32 * SCW_);
    const h8* W1f8 = (const h8*)W1f;
    const bool full = (t0 + 32) <= len;  // wave-uniform
    const int tb = t0 + th * 16;

    f4 acc[2][8] = {};

    const float* xptr = x + ((size_t)b * C_ + c_base + kc) * T_ + tb;

    for (int step = 0; step < 12; ++step) {
        float xs[16];
        *(float4*)&xs[0]  = ((const float4*)xptr)[0];
        *(float4*)&xs[4]  = ((const float4*)xptr)[1];
        *(float4*)&xs[8]  = ((const float4*)xptr)[2];
        *(float4*)&xs[12] = ((const float4*)xptr)[3];
        xptr += 32 * (size_t)T_;
        const float2 cr =
            carryT[((size_t)b * M32_ + m) * C_ + c_base + step * 32 + kc];

        // lane totals over its 16 t
        float ls1 = 0.f, ls2 = 0.f;
        if (full) {
#pragma unroll
            for (int j = 0; j < 16; ++j) { ls1 += xs[j]; ls2 += xs[j] * xs[j]; }
        } else {
#pragma unroll
            for (int j = 0; j < 16; ++j) {
                float mv = (tb + j < len) ? xs[j] : 0.f;
                ls1 += mv; ls2 += mv * xs[j];
            }
        }
        const float o1 = __shfl_xor(ls1, 1, 64);
        const float o2 = __shfl_xor(ls2, 1, 64);
        float r1 = cr.x + (th ? o1 : 0.f);
        float r2 = cr.y + (th ? o2 : 0.f);
#pragma unroll
        for (int j = 0; j < 16; ++j) {
            const float xval = xs[j];
            const float mv = (full || (tb + j < len)) ? xval : 0.f;
            r1 += mv; r2 += mv * xval;
            const float rn = __builtin_amdgcn_rcpf((float)min(tb + j + 1, len));
            const float mn = r1 * rn;
            const float var = r2 * rn - mn * mn;
            const float sd = sqrtf(fmaxf(var, 1e-12f));
            const int row = th * 16 + j;
            sc[row * SCW_ + kc]      = (_Float16)xval;
            sc[row * SCW_ + 32 + kc] = (_Float16)mn;
            sc[row * SCW_ + 64 + kc] = (_Float16)sd;
        }
        // within-wave LDS ordering via lgkmcnt; no barrier needed
        const int t15 = lane & 15, k8 = lane >> 4;
        const int kbS = w * 12 + step;
#pragma unroll
        for (int p = 0; p < 3; ++p) {
            h8 bf0 = *(const h8*)&sc[t15 * SCW_ + p * 32 + k8 * 8];
            h8 bf1 = *(const h8*)&sc[(16 + t15) * SCW_ + p * 32 + k8 * 8];
            const int kb = p * 48 + kbS;
#pragma unroll
            for (int ii = 0; ii < 8; ++ii) {
                h8 af = W1f8[(size_t)(kb * 8 + ii) * 64 + lane];
                acc[0][ii] = __builtin_amdgcn_mfma_f32_16x16x32_f16(af, bf0, acc[0][ii], 0, 0, 0);
                acc[1][ii] = __builtin_amdgcn_mfma_f32_16x16x32_f16(af, bf1, acc[1][ii], 0, 0, 0);
            }
        }
    }

    // ---- 4-way split-K reduce cascade + epilogue (4 barriers, loop-free) ----
    __syncthreads();
    float* red = (float*)smem;
    if (w >= 2) {
        float* r = red + (size_t)(w - 2) * 4096;
#pragma unroll
        for (int nn = 0; nn < 2; ++nn)
#pragma unroll
            for (int ii = 0; ii < 8; ++ii)
#pragma unroll
                for (int rg = 0; rg < 4; ++rg)
                    r[(nn * 32 + ii * 4 + rg) * 64 + lane] = acc[nn][ii][rg];
    }
    __syncthreads();
    if (w < 2) {
        float* r = red + (size_t)w * 4096;
#pragma unroll
        for (int nn = 0; nn < 2; ++nn)
#pragma unroll
            for (int ii = 0; ii < 8; ++ii)
#pragma unroll
                for (int rg = 0; rg < 4; ++rg)
                    acc[nn][ii][rg] += r[(nn * 32 + ii * 4 + rg) * 64 + lane];
    }
    __syncthreads();
    if (w == 1) {
#pragma unroll
        for (int nn = 0; nn < 2; ++nn)
#pragma unroll
            for (int ii = 0; ii < 8; ++ii)
#pragma unroll
                for (int rg = 0; rg < 4; ++rg)
                    red[(nn * 32 + ii * 4 + rg) * 64 + lane] = acc[nn][ii][rg];
    }
    __syncthreads();
    if (w == 0) {
        const int q = lane >> 4;
#pragma unroll
        for (int nn = 0; nn < 2; ++nn) {
            float pr = 0.f;
#pragma unroll
            for (int ii = 0; ii < 8; ++ii)
#pragma unroll
                for (int rg = 0; rg < 4; ++rg) {
                    float v = acc[nn][ii][rg] + red[(nn * 32 + ii * 4 + rg) * 64 + lane];
                    int a = ii * 16 + q * 4 + rg;
                    pr += tanhf(v + s_b1[a]) * s_w2[a];
                }
            pr += __shfl_xor(pr, 16, 64);
            pr += __shfl_xor(pr, 32, 64);
            if (lane < 16)
                logits[(size_t)b * T_ + t0 + nn * 16 + lane] = pr;
        }
    }
}

// ---------------- kernel 3: softmax prep (e, cumsum Z) per b ----------------
// b2 and the max-subtraction cancel in the e/Z ratios used downstream.
__global__ __launch_bounds__(1024) void k3_softmax(
    const float* __restrict__ logits, float* __restrict__ earr,
    float* __restrict__ zarr)
{
    __shared__ float wsum[16];
    const int b = blockIdx.x, tid = threadIdx.x, lane = tid & 63, w = tid >> 6;
    float4 v = *(const float4*)(logits + (size_t)b * T_ + tid * 4);
    float e0 = expf(v.x), e1 = expf(v.y), e2 = expf(v.z), e3 = expf(v.w);
    float s = (e0 + e1) + (e2 + e3);
    float V = s;
#pragma unroll
    for (int d = 1; d < 64; d <<= 1) {
        float o = __shfl_up(V, d, 64);
        if (lane >= d) V += o;
    }
    if (lane == 63) wsum[w] = V;
    __syncthreads();
    float wb = 0.f;
#pragma unroll
    for (int i = 0; i < 16; ++i) wb += (i < w) ? wsum[i] : 0.f;
    float run = wb + (V - s);
    float4 ev, zv;
    ev.x = e0; run += e0; zv.x = run;
    ev.y = e1; run += e1; zv.y = run;
    ev.z = e2; run += e2; zv.z = run;
    ev.w = e3; run += e3; zv.w = run;
    *(float4*)(earr + (size_t)b * T_ + tid * 4) = ev;
    *(float4*)(zarr + (size_t)b * T_ + tid * 4) = zv;
}

// ---------------- kernel 4: weighted running mean/std + final reduce --------
__global__ __launch_bounds__(256) void k4_wstats(
    const float* __restrict__ x, const float* __restrict__ earr,
    const float* __restrict__ zarr, float* __restrict__ out)
{
    const int rowid = blockIdx.x * 4 + (threadIdx.x >> 6);
    const int lane  = threadIdx.x & 63;
    const int b = rowid / C_;
    const int c = rowid - b * C_;
    const float* xr = x + (size_t)rowid * T_;
    const float* er = earr + (size_t)b * T_;
    const float* zr = zarr + (size_t)b * T_;
    float am = 0.f, asd = 0.f;
    float baseS = 0.f, baseD = 0.f;
#pragma unroll
    for (int g = 0; g < 16; ++g) {
        const int off = g * 256 + lane * 4;
        float4 xv = *(const float4*)(xr + off);
        float4 ev = *(const float4*)(er + off);
        float4 zv = *(const float4*)(zr + off);
        float s0 = ev.x * xv.x;
        float s1 = s0 + ev.y * xv.y;
        float s2 = s1 + ev.z * xv.z;
        float s3 = s2 + ev.w * xv.w;
        float V = s3;
#pragma unroll
        for (int d = 1; d < 64; d <<= 1) {
            float o = __shfl_up(V, d, 64);
            if (lane >= d) V += o;
        }
        const float Sx = baseS + (V - s3);
        baseS += __shfl(V, 63, 64);
        const float rz0 = __builtin_amdgcn_rcpf(zv.x);
        const float rz1 = __builtin_amdgcn_rcpf(zv.y);
        const float rz2 = __builtin_amdgcn_rcpf(zv.z);
        const float rz3 = __builtin_amdgcn_rcpf(zv.w);
        const float wm0 = (Sx + s0) * rz0;
        const float wm1 = (Sx + s1) * rz1;
        const float wm2 = (Sx + s2) * rz2;
        const float wm3 = (Sx + s3) * rz3;
        am += (wm0 + wm1) + (wm2 + wm3);
        const float d0 = xv.x - wm0;
        const float d1 = xv.y - wm1;
        const float d2 = xv.z - wm2;
        const float d3 = xv.w - wm3;
        float q0 = ev.x * d0 * d0;
        float q1 = q0 + ev.y * d1 * d1;
        float q2 = q1 + ev.z * d2 * d2;
        float q3 = q2 + ev.w * d3 * d3;
        float W = q3;
#pragma unroll
        for (int d = 1; d < 64; d <<= 1) {
            float o = __shfl_up(W, d, 64);
            if (lane >= d) W += o;
        }
        const float Dx = baseD + (W - q3);
        baseD += __shfl(W, 63, 64);
        const float v0 = (Dx + q0) * rz0;
        const float v1 = (Dx + q1) * rz1;
        const float v2 = (Dx + q2) * rz2;
        const float v3 = (Dx + q3) * rz3;
        asd += (sqrtf(fmaxf(v0, 1e-12f)) + sqrtf(fmaxf(v1, 1e-12f)))
             + (sqrtf(fmaxf(v2, 1e-12f)) + sqrtf(fmaxf(v3, 1e-12f)));
    }
#pragma unroll
    for (int d = 1; d < 64; d <<= 1) {
        am  += __shfl_xor(am, d, 64);
        asd += __shfl_xor(asd, d, 64);
    }
    if (lane == 0) {
        out[(size_t)b * (2 * C_) + c]      = am  * (1.f / 4096.f);
        out[(size_t)b * (2 * C_) + C_ + c] = asd * (1.f / 4096.f);
    }
}

extern "C" void kernel_launch(void* const* d_in, const int* in_sizes, int n_in,
                              void* d_out, int out_size, void* d_ws, size_t ws_size,
                              hipStream_t stream) {
    const float* x    = (const float*)d_in[0];
    const int*   lens = (const int*)d_in[1];
    const float* W1   = (const float*)d_in[2];
    const float* b1   = (const float*)d_in[3];
    const float* W2   = (const float*)d_in[4];
    float* out = (float*)d_out;
    char* ws = (char*)d_ws;

    // ws layout (~14.2 MB):
    float2*    carryT = (float2*)ws;                     // 8*128*1536*8 = 12,582,912
    _Float16*  W1f    = (_Float16*)(ws + 12582912);      //                1,179,648
    float*     logits = (float*)(ws + 13762560);         //                  131,072
    float*     earr   = (float*)(ws + 13893632);         //                  131,072
    float*     zarr   = (float*)(ws + 14024704);         //                  131,072

    k0_pack   <<<(A_ * K3_ + 255) / 256, 256, 0, stream>>>(W1, W1f);
    k1_carryT <<<(B_ * C_) / 4, 256, 0, stream>>>(x, lens, carryT);
    k2g       <<<B_ * M32_, 256, 0, stream>>>(x, lens, carryT, W1f, b1, W2, logits);
    k3_softmax<<<B_, 1024, 0, stream>>>(logits, earr, zarr);
    k4_wstats <<<(B_ * C_) / 4, 256, 0, stream>>>(x, earr, zarr, out);
}